// Round 5
// baseline (152.283 us; speedup 1.0000x reference)
//
#include <hip/hip_runtime.h>
#include <hip/hip_bf16.h>
#include <hip/hip_fp16.h>
#include <math.h>

// Problem constants (from reference)
#define B_   64
#define L_   512
#define V_   20000
#define P_   150
#define M_   6
#define KDIM 300
#define NOUT 750          // P_ * (M_-1) used transition scores
#define CWS  752          // padded row stride (16B-aligned float4 rows)
#define NEGF (-1.0e9f)

// f32 fallback GEMM tiling
#define BM 128
#define BN 128
#define BK 16
#define LDP 132

// MFMA path constants
#define KP 320            // K padded: 10 tiles of 32
#define NIT 10            // K-iters
#define NVG 157           // v-groups of 128
#define NJ  6             // n-groups of 128
#define TILE_U4 1024      // uint4 per (group,it) tile: [s 2][q 4][row 128]
#define SA 1024.0f        // emb scale (keeps lo-split out of fp16 subnormals)
#define SB 16384.0f       // diags scale
#define INV24 (5.9604644775390625e-8f)   // 2^-24

// Scan chunking
#define TCHUNK 32
#define NCHUNK (L_ / TCHUNK)   // 16
#define WARM   5
#define CS_STRIDE 160
#define KVBUF 3           // k2 pipeline depth-2 -> 3 LDS buffers

typedef _Float16 f16x8 __attribute__((ext_vector_type(8)));
typedef float f32x16 __attribute__((ext_vector_type(16)));

__device__ __forceinline__ float logsigf(float x) {
    // matches jax: -softplus(-x) = min(x,0) - log1p(exp(-|x|))
    return fminf(x, 0.f) - log1pf(expf(-fabsf(x)));
}

// fast variant for k1m epilogue: v_exp_f32/v_log_f32, abs err ~6e-8 (flip-safe budget)
__device__ __forceinline__ float logsigf_fast(float x) {
    return fminf(x, 0.f) - __logf(1.f + __expf(-fabsf(x)));
}

// async global->LDS, 16 B per lane; LDS dst = wave-uniform base + lane*16
__device__ __forceinline__ void gload_lds16(const void* gp, void* lp) {
    __builtin_amdgcn_global_load_lds(
        (const __attribute__((address_space(1))) unsigned int*)gp,
        (__attribute__((address_space(3))) unsigned int*)lp, 16, 0, 0);
}

// ---------------- MFMA path ----------------

// P12 (fused p1+p2, one launch):
// blocks [0, NVG*5): emb [300][20000] -> fp16 hi/lo splits, DMA-tiled
//   a_t[g 157][it 10][s 2][q 4][row 128] uint4.
// blocks [NVG*5, NVG*5+60): diags (dpm-mapped, scaled) -> b_t[j 6][it 10][s2][q4][row128].
__global__ __launch_bounds__(256) void p12_split(
    const float* __restrict__ emb, const float* __restrict__ diags,
    uint4* __restrict__ a_t, uint4* __restrict__ b_t)
{
    __shared__ float T[64][132];
    const int t   = threadIdx.x;
    const int bid = blockIdx.x;

    if (bid < NVG * 5) {
        // ---- p1 part ----
        const int gx = bid % NVG;
        const int ky = bid / NVG;            // 0..4
        const int v0 = gx * 128;
        const int k0 = ky * 64;

        #pragma unroll
        for (int pass = 0; pass < 8; ++pass) {
            int flat = pass * 256 + t;
            int krow = flat >> 5;
            int c4   = (flat & 31) * 4;
            int kg   = k0 + krow;
            int v    = v0 + c4;
            float4 f = {0.f, 0.f, 0.f, 0.f};
            if (kg < KDIM && v + 3 < V_)
                f = *(const float4*)(emb + (size_t)kg * V_ + v);
            *(float4*)&T[krow][c4] = f;
        }
        __syncthreads();

        const int vv = t >> 1;
        const int kh = (t & 1) * 32;
        const int it = ky * 2 + (kh >> 5);
        const int v  = v0 + vv;
        if (v < V_) {
            union { ushort u[8]; uint4 q; } H[4], Lo[4];
            #pragma unroll
            for (int i = 0; i < 32; ++i) {
                float x = T[kh + i][vv] * SA;
                __half h = __float2half_rn(x);
                float rem = x - __half2float(h);
                H[i >> 3].u[i & 7]  = __half_as_ushort(h);
                Lo[i >> 3].u[i & 7] = __half_as_ushort(__float2half_rn(rem));
            }
            uint4* tile = a_t + ((size_t)gx * NIT + it) * TILE_U4;
            #pragma unroll
            for (int c = 0; c < 4; ++c) {
                tile[      c * 128 + vv] = H[c].q;
                tile[512 + c * 128 + vv] = Lo[c].q;
            }
        }
    } else {
        // ---- p2 part ----
        const int bidx = bid - NVG * 5;      // j*10 + it, 0..59
        const int it   = bidx % NIT;
        const int j    = bidx / NIT;
        const int row  = t >> 1;
        const int qh   = (t & 1) * 2;
        const int n    = j * 128 + row;
        const bool nok = (n < NOUT);
        const int pm   = nok ? ((n / 5) * 6 + (n % 5)) : 0;
        uint4* tile = b_t + (size_t)bidx * TILE_U4;
        #pragma unroll
        for (int qq = 0; qq < 2; ++qq) {
            int q = qh + qq;
            union { ushort u[8]; uint4 v; } H, Lo;
            #pragma unroll
            for (int e = 0; e < 8; ++e) {
                int k = it * 32 + q * 8 + e;
                float x = (nok && k < KDIM) ? diags[(size_t)pm * KDIM + k] * SB : 0.f;
                __half h = __float2half_rn(x);
                float rem = x - __half2float(h);
                H.u[e]  = __half_as_ushort(h);
                Lo.u[e] = __half_as_ushort(__float2half_rn(rem));
            }
            tile[      q * 128 + row] = H.v;
            tile[512 + q * 128 + row] = Lo.v;
        }
    }
}

// K1 (MFMA, round-5): C = a1@b1 + a1@b2 + a2@b1 (fp16 split-f32), 256x256 tile.
// A staged via gload_lds (double-buffered, 2x32 KB); B read DIRECTLY from
// global into registers (b_t = 983 KB, permanently L2-resident; coalesced
// dwordx4 per fragment).
//
// History:
//  r0/r1: 128x128 gload_lds, 2 blk/CU -> 50 us. DMA ~10 B/cyc/CU from L3;
//         compute hidden by the OTHER block (TLP), not the double-buffer.
//  r2/r3: reg-staging spilled (allocator targeted 4 waves/EU; 108/128 VGPR).
//  r4:    256x256 gload_lds, 1 blk/CU (grid 237<256): DMA issue-stall
//         serializes with compute (9.2k cyc/iter = 6k DMA + 3.2k MFMA) ->
//         91.6 us. DMA rate confirmed ~10 B/cyc/CU, invariant.
//  r5 (this): halve the DMA volume -- A only (32 KB/iter = 3.2k cyc, matches
//         compute 3.2k). B frags (8 KB/iter/CU) via plain VMEM, issued FIRST
//         so the compiler's B-wait is vmcnt(4), never draining the A-DMA.
//         A wave stalled at a full DMA queue yields its SIMD to MFMA-phase
//         waves -> per-iter ~ max(DMA, compute). LDS 64 KB. VGPR ~200 under
//         the pinned 2-waves/EU 256 budget.
// Spill check: WRITE_SIZE must stay ~60-63 MB. Same MFMA order -> bitwise-same C.
__global__ __attribute__((amdgpu_waves_per_eu(2, 2))) __launch_bounds__(512)
void k1m_gemm(
    const uint4* __restrict__ a_t, const uint4* __restrict__ b_t,
    const float* __restrict__ bias, const float* __restrict__ wildc,
    float* __restrict__ cw)
{
    const int bid = blockIdx.x;              // 0..239
    const int c   = bid / 24;                // gp-chunk 0..9
    const int r   = bid % 24;
    const int gp  = c * 8 + (r & 7);         // 256-row group-pair 0..79
    const int h   = r >> 3;                  // n-block 0..2 (256 cols each)
    if (gp >= 79) return;                    // gp=79 invalid (3 idle blocks)

    __shared__ uint4 sm[2][2048];            // 2 x 32 KB (A only)
    const int t    = threadIdx.x;            // 0..511
    const int lane = t & 63;
    const int w    = t >> 6;                 // wave 0..7
    const int wr   = w >> 2;                 // 128-row half (== A group select)
    const int wc   = w & 3;                  // 64-col quarter
    const int fk16 = lane >> 5;
    const int fm   = lane & 31;

    const int ga = 2 * gp;
    const int gb = (2 * gp + 1 < NVG) ? (2 * gp + 1) : (NVG - 1); // clamp; dup rows guarded at write
    // A staging: 32 KB/iter = 8 sections of 4 KB; wave w stages section w:
    //   [A-g0 hi 8K][A-g0 lo 8K][A-g1 hi 8K][A-g1 lo 8K], linear in LDS.
    const uint4* asec =
        ((w < 4) ? a_t + (size_t)ga * NIT * TILE_U4
                 : a_t + (size_t)gb * NIT * TILE_U4) + (w & 3) * 256 + lane;

    // B fragment base pointers (per cj); per-(it,s) offset added in-loop.
    const uint4* bb[2];
    #pragma unroll
    for (int cj = 0; cj < 2; ++cj) {
        const int colb = wc * 64 + cj * 32;
        bb[cj] = b_t + (size_t)(2 * h + (colb >> 7)) * NIT * TILE_U4
                     + (colb & 127) + fm;
    }

    f32x16 acc[4][2];
    #pragma unroll
    for (int i = 0; i < 4; ++i)
        #pragma unroll
        for (int jj = 0; jj < 2; ++jj)
            #pragma unroll
            for (int e = 0; e < 16; ++e) acc[i][jj][e] = 0.f;

    // prologue: stage A it=0 into buffer 0 (4 x 1 KB per wave)
    #pragma unroll
    for (int i = 0; i < 4; ++i)
        gload_lds16(asec + i * 64, &sm[0][w * 256 + i * 64 + lane]);

    int cur = 0;
    for (int it = 0; it < NIT; ++it) {
        __syncthreads();                     // drains A-DMA for buf[cur]

        // 1) B fragment loads for THIS iter (VMEM, L2-resident) -- issued
        //    BEFORE the A-DMA so the MFMA B-wait never drains the prefetch.
        f16x8 B1[2][2], B2[2][2];            // [s][cj]
        #pragma unroll
        for (int s = 0; s < 2; ++s) {
            const int q = s * 2 + fk16;
            #pragma unroll
            for (int cj = 0; cj < 2; ++cj) {
                const uint4* bp = bb[cj] + (size_t)it * TILE_U4 + q * 128;
                B1[s][cj] = *(const f16x8*)bp;
                B2[s][cj] = *(const f16x8*)(bp + 512);
            }
        }

        // 2) async A prefetch for it+1 into the other buffer
        if (it + 1 < NIT) {
            const uint4* ap = asec + (size_t)(it + 1) * TILE_U4;
            #pragma unroll
            for (int i = 0; i < 4; ++i)
                gload_lds16(ap + i * 64, &sm[cur ^ 1][w * 256 + i * 64 + lane]);
        }

        // 3) compute iter it: A from sm[cur] ([A-g0 1024][A-g1 1024] u4,
        //    native [s 2][q 4][row 128] per group), B from registers
        const uint4* smc = &sm[cur][0];
        #pragma unroll
        for (int s = 0; s < 2; ++s) {
            const int q = s * 2 + fk16;
            f16x8 A1[4], A2[4];
            #pragma unroll
            for (int ri = 0; ri < 4; ++ri) {
                const int ao = wr * 1024 + q * 128 + ri * 32 + fm;
                A1[ri] = *(const f16x8*)&smc[ao];
                A2[ri] = *(const f16x8*)&smc[ao + 512];
            }
            #pragma unroll
            for (int ri = 0; ri < 4; ++ri)
                #pragma unroll
                for (int cj = 0; cj < 2; ++cj) {
                    acc[ri][cj] = __builtin_amdgcn_mfma_f32_32x32x16_f16(A1[ri], B1[s][cj], acc[ri][cj], 0, 0, 0);
                    acc[ri][cj] = __builtin_amdgcn_mfma_f32_32x32x16_f16(A1[ri], B2[s][cj], acc[ri][cj], 0, 0, 0);
                    acc[ri][cj] = __builtin_amdgcn_mfma_f32_32x32x16_f16(A2[ri], B1[s][cj], acc[ri][cj], 0, 0, 0);
                }
        }
        cur ^= 1;
    }

    // epilogue: C/D layout col=lane&31, row=(e&3)+8*(e>>2)+4*(lane>>5)
    float biasv[2], lwv[2]; int ncol[2]; bool nok[2];
    #pragma unroll
    for (int cj = 0; cj < 2; ++cj) {
        int n = h * 256 + wc * 64 + cj * 32 + fm;
        ncol[cj] = n;
        nok[cj]  = (n < NOUT);
        int nc = nok[cj] ? n : 0;
        int pm = (nc / 5) * 6 + (nc % 5);
        biasv[cj] = bias[pm];
        lwv[cj]   = logsigf_fast(wildc[nc]);
    }
    const int v0 = gp * 256;
    #pragma unroll
    for (int ri = 0; ri < 4; ++ri) {
        int vbase = v0 + wr * 128 + ri * 32 + 4 * fk16;
        #pragma unroll
        for (int cj = 0; cj < 2; ++cj) {
            if (!nok[cj]) continue;
            #pragma unroll
            for (int e = 0; e < 16; ++e) {
                int v = vbase + (e & 3) + 8 * (e >> 2);
                if (v < V_) {
                    float val = acc[ri][cj][e] * INV24 + biasv[cj];
                    cw[(size_t)v * CWS + ncol[cj]] = fmaxf(logsigf_fast(val), lwv[cj]);
                }
            }
        }
    }
}

// ---------------- f32 fallback (round-2 kernel) ----------------

__global__ __launch_bounds__(256) void k1_gemm_cw(
    const float* __restrict__ emb,
    const float* __restrict__ diags,
    const float* __restrict__ bias,
    const float* __restrict__ wildc,
    float* __restrict__ cw)
{
    __shared__ float As[BK][LDP];
    __shared__ float Bs[BK][LDP];

    const int tid = threadIdx.x;
    const int v0 = blockIdx.x * BM;
    const int n0 = blockIdx.y * BN;
    const int tx = tid & 15;
    const int ty = tid >> 4;

    float acc[8][8];
    #pragma unroll
    for (int i = 0; i < 8; ++i)
        #pragma unroll
        for (int j = 0; j < 8; ++j) acc[i][j] = 0.f;

    const int a_k = tid >> 4;
    const int a_v = (tid & 15) * 8;
    const int b_n   = tid >> 1;
    const int b_kof = (tid & 1) * 8;

    int  brow;
    bool bval;
    {
        int n = n0 + b_n;
        bval = (n < NOUT);
        brow = bval ? ((n / 5) * 6 + (n % 5)) : 0;
    }

    for (int k0 = 0; k0 < KDIM; k0 += BK) {
        {
            float4 f0 = {0,0,0,0}, f1 = {0,0,0,0};
            int k = k0 + a_k;
            if (k < KDIM) {
                const float* src = emb + (size_t)k * V_ + v0 + a_v;
                if (v0 + a_v + 3 < V_) f0 = *(const float4*)src;
                if (v0 + a_v + 7 < V_) f1 = *(const float4*)(src + 4);
            }
            *(float4*)&As[a_k][a_v]     = f0;
            *(float4*)&As[a_k][a_v + 4] = f1;
        }
        {
            float4 f = {0,0,0,0}, g = {0,0,0,0};
            if (bval) {
                const float* src = diags + (size_t)brow * KDIM + k0 + b_kof;
                if (k0 + b_kof + 3 < KDIM) f = *(const float4*)src;
                if (k0 + b_kof + 7 < KDIM) g = *(const float4*)(src + 4);
            }
            Bs[b_kof + 0][b_n] = f.x;
            Bs[b_kof + 1][b_n] = f.y;
            Bs[b_kof + 2][b_n] = f.z;
            Bs[b_kof + 3][b_n] = f.w;
            Bs[b_kof + 4][b_n] = g.x;
            Bs[b_kof + 5][b_n] = g.y;
            Bs[b_kof + 6][b_n] = g.z;
            Bs[b_kof + 7][b_n] = g.w;
        }
        __syncthreads();
        #pragma unroll
        for (int k = 0; k < BK; ++k) {
            float4 a0 = *(const float4*)&As[k][tx * 4];
            float4 a1 = *(const float4*)&As[k][64 + tx * 4];
            float4 b0 = *(const float4*)&Bs[k][ty * 8];
            float4 b1 = *(const float4*)&Bs[k][ty * 8 + 4];
            float av[8] = {a0.x, a0.y, a0.z, a0.w, a1.x, a1.y, a1.z, a1.w};
            float bv[8] = {b0.x, b0.y, b0.z, b0.w, b1.x, b1.y, b1.z, b1.w};
            #pragma unroll
            for (int i = 0; i < 8; ++i)
                #pragma unroll
                for (int j = 0; j < 8; ++j)
                    acc[i][j] = fmaf(av[i], bv[j], acc[i][j]);
        }
        __syncthreads();
    }

    float biasv[8], lwv[8];
    #pragma unroll
    for (int j = 0; j < 8; ++j) {
        int n  = n0 + ty * 8 + j;
        int nc = (n < NOUT) ? n : 0;
        int pm = (nc / 5) * 6 + (nc % 5);
        biasv[j] = bias[pm];
        lwv[j]   = logsigf(wildc[nc]);
    }
    #pragma unroll
    for (int i = 0; i < 8; ++i) {
        int v = v0 + ((i < 4) ? (tx * 4 + i) : (64 + tx * 4 + (i - 4)));
        if (v >= V_) continue;
        float r[8];
        #pragma unroll
        for (int j = 0; j < 8; ++j)
            r[j] = fmaxf(logsigf(acc[i][j] + biasv[j]), lwv[j]);
        float* dst = cw + (size_t)v * CWS + n0 + ty * 8;
        if (n0 + ty * 8     < NOUT) *(float4*)dst       = make_float4(r[0], r[1], r[2], r[3]);
        if (n0 + ty * 8 + 4 < NOUT) *(float4*)(dst + 4) = make_float4(r[4], r[5], r[6], r[7]);
    }
}

// ---------------- scan (pipelined LDS staging) + finalize ----------------

// 3-buffer, depth-2 pipeline with counted s_waitcnt vmcnt(3) + raw s_barrier
// (one barrier per round). Bit-identical values.
__global__ __launch_bounds__(192) void k2_scan(
    const int* __restrict__ docs,
    const int* __restrict__ doc_lens,
    const float* __restrict__ cw,
    float* __restrict__ cs)
{
    const int ci = blockIdx.x;
    const int b  = blockIdx.y;
    const int t0 = ci * TCHUNK;
    const int ts = (t0 >= WARM) ? (t0 - WARM) : 0;
    const int dl = doc_lens[b];
    const int te = min(t0 + TCHUNK, dl);
    const int nt = te - ts;              // tokens to process (may be <= 0)

    __shared__ int   toks[TCHUNK + WARM];
    __shared__ float rows[KVBUF][3][768];   // 27 KB: [buf][row-in-round][752 used]

    const int t    = threadIdx.x;
    const int lane = t & 63;
    const int w    = t >> 6;             // wave 0..2

    if (t < TCHUNK + WARM) {
        int tt = ts + t;
        toks[t] = docs[b * L_ + min(tt, L_ - 1)];
    }
    __syncthreads();                     // toks ready; drains all prior vmem

    const int p      = t;                // pattern if < P_
    const int e      = (p < 50) ? 3 : (p < 100) ? 4 : 5;
    const int warm_n = t0 - ts;
    float h1 = NEGF, h2 = NEGF, h3 = NEGF, h4 = NEGF, h5 = NEGF, sc = NEGF;

    const int nrounds = (nt > 0) ? (nt + 2) / 3 : 0;

    // prologue: issue DMA for rounds 0 and 1 (wave w stages row w of a round)
    for (int r0 = 0; r0 < 2; ++r0) {
        if (r0 >= nrounds) break;
        int idx = min(3 * r0 + w, nt - 1);
        const char* rowp = (const char*)(cw + (size_t)toks[idx] * CWS);
        char* lbase = (char*)&rows[r0][w][0];
        #pragma unroll
        for (int jj = 0; jj < 3; ++jj)
            gload_lds16(rowp + jj * 1024 + lane * 16,
                        lbase + jj * 1024 + lane * 16);
    }

    int bufc = 0;
    for (int r = 0; r < nrounds; ++r) {
        // drain THIS round's DMA only; keep round r+1's 3 loads in flight
        if (r + 1 < nrounds) {
            asm volatile("s_waitcnt vmcnt(3)" ::: "memory");
        } else {
            asm volatile("s_waitcnt vmcnt(0)" ::: "memory");
        }
        __builtin_amdgcn_s_barrier();
        asm volatile("" ::: "memory");   // fence: no rows-read hoists above barrier

        if (r + 2 < nrounds) {           // prefetch round r+2 (buffer of round r-1)
            int rn  = r + 2;
            int idx = min(3 * rn + w, nt - 1);
            const char* rowp = (const char*)(cw + (size_t)toks[idx] * CWS);
            int bn = bufc + 2; if (bn >= KVBUF) bn -= KVBUF;
            char* lbase = (char*)&rows[bn][w][0];
            #pragma unroll
            for (int jj = 0; jj < 3; ++jj)
                gload_lds16(rowp + jj * 1024 + lane * 16,
                            lbase + jj * 1024 + lane * 16);
        }

        #pragma unroll
        for (int u = 0; u < 3; ++u) {
            int i2 = 3 * r + u;
            if (i2 >= nt) break;
            if (p < P_) {
                const float* rp = &rows[bufc][u][p * 5];
                float c0 = rp[0], c1 = rp[1], c2 = rp[2], c3 = rp[3], c4 = rp[4];
                h5 = h4 + c4;
                h4 = h3 + c3;
                h3 = h2 + c2;
                h2 = h1 + c1;
                h1 = c0;                 // h0 = 0 always
                if (i2 >= warm_n) {
                    float esv = (e == 3) ? h3 : (e == 4) ? h4 : h5;
                    sc = fmaxf(sc, esv);
                }
            }
        }
        bufc = (bufc + 1 == KVBUF) ? 0 : bufc + 1;
        // no second barrier: the barrier at top of round r+1 orders
        // compute(r) (all waves) before DMA(r+3) overwrites buf[r%3]
    }
    if (p < P_) cs[(size_t)(b * NCHUNK + ci) * CS_STRIDE + p] = sc;
}

__device__ __forceinline__ float block_sum192(float v, volatile float* red, int tid) {
    #pragma unroll
    for (int off = 32; off > 0; off >>= 1) v += __shfl_down(v, off, 64);
    __syncthreads();
    if ((tid & 63) == 0) red[tid >> 6] = v;
    __syncthreads();
    return red[0] + red[1] + red[2];
}

__global__ __launch_bounds__(192) void k3_final(
    const float* __restrict__ cs,
    const float* __restrict__ gamma,
    const float* __restrict__ beta,
    const float* __restrict__ lw,
    const float* __restrict__ lb,
    float* __restrict__ out)
{
    __shared__ float red[3];
    const int b   = blockIdx.x;
    const int tid = threadIdx.x;
    float s = 0.f;
    if (tid < P_) {
        float m = NEGF;
        const float* row = cs + (size_t)b * NCHUNK * CS_STRIDE + tid;
        #pragma unroll
        for (int ci = 0; ci < NCHUNK; ++ci) m = fmaxf(m, row[ci * CS_STRIDE]);
        s = expf(m);
    }
    float mu = block_sum192(s, red, tid) * (1.f / P_);
    float d  = (tid < P_) ? (s - mu) : 0.f;
    float var = block_sum192(d * d, red, tid) * (1.f / P_);
    float bin = 0.f;
    if (tid < P_) {
        float norm = (s - mu) * rsqrtf(var + 1e-5f) * gamma[tid] + beta[tid];
        bin = (norm > 0.f) ? 1.f : 0.f;
    }
    float o0 = block_sum192((tid < P_) ? bin * lw[tid]      : 0.f, red, tid);
    float o1 = block_sum192((tid < P_) ? bin * lw[P_ + tid] : 0.f, red, tid);
    if (tid == 0) {
        out[b * 2 + 0] = o0 + lb[0];
        out[b * 2 + 1] = o1 + lb[1];
    }
}

extern "C" void kernel_launch(void* const* d_in, const int* in_sizes, int n_in,
                              void* d_out, int out_size, void* d_ws, size_t ws_size,
                              hipStream_t stream)
{
    const int*   docs  = (const int*)  d_in[0];
    const int*   dlens = (const int*)  d_in[1];
    const float* emb   = (const float*)d_in[2];
    const float* diags = (const float*)d_in[3];
    const float* bias  = (const float*)d_in[4];
    const float* wildc = (const float*)d_in[5];
    const float* gamma = (const float*)d_in[6];
    const float* beta  = (const float*)d_in[7];
    const float* lw    = (const float*)d_in[8];
    const float* lb    = (const float*)d_in[9];
    float* out = (float*)d_out;

    // ws layout: cw | cs | a_t | b_t
    const size_t cw_b = (size_t)V_ * CWS * 4;                 // 60,160,000
    const size_t cs_b = (size_t)B_ * NCHUNK * CS_STRIDE * 4;  // 655,360
    const size_t at_b = (size_t)NVG * NIT * TILE_U4 * 16;     // 25,722,880
    const size_t bt_b = (size_t)NJ  * NIT * TILE_U4 * 16;     // 983,040
    const size_t need = cw_b + cs_b + at_b + bt_b;

    char* base = (char*)d_ws;
    float* cw = (float*)base;
    float* cs = (float*)(base + cw_b);
    uint4* at = (uint4*)(base + cw_b + cs_b);
    uint4* bt = (uint4*)(base + cw_b + cs_b + at_b);

    if (ws_size >= need) {
        p12_split<<<NVG * 5 + NJ * NIT, 256, 0, stream>>>(emb, diags, at, bt);
        // 240 blocks: 80 group-pair chunks x 3 n-blocks, XCD-colocated siblings
        k1m_gemm<<<240, 512, 0, stream>>>(at, bt, bias, wildc, cw);
    } else {
        dim3 g1((V_ + BM - 1) / BM, (NOUT + BN - 1) / BN);
        k1_gemm_cw<<<g1, 256, 0, stream>>>(emb, diags, bias, wildc, cw);
    }

    dim3 g2(NCHUNK, B_);
    k2_scan<<<g2, 192, 0, stream>>>(docs, dlens, cw, cs);
    k3_final<<<B_, 192, 0, stream>>>(cs, gamma, beta, lw, lb, out);
}

// Round 6
// 151.631 us; speedup vs baseline: 1.0043x; 1.0043x over previous
//
#include <hip/hip_runtime.h>
#include <hip/hip_bf16.h>
#include <hip/hip_fp16.h>
#include <math.h>

// Problem constants (from reference)
#define B_   64
#define L_   512
#define V_   20000
#define P_   150
#define M_   6
#define KDIM 300
#define NOUT 750          // P_ * (M_-1) used transition scores
#define CWS  752          // padded row stride (16B-aligned float4 rows)
#define NEGF (-1.0e9f)

// f32 fallback GEMM tiling
#define BM 128
#define BN 128
#define BK 16
#define LDP 132

// MFMA path constants
#define KP 320            // K padded: 10 tiles of 32
#define NIT 10            // K-iters
#define NVG 157           // v-groups of 128
#define NJ  6             // n-groups of 128
#define TILE_U4 1024      // uint4 per (group,it) tile: [s 2][q 4][row 128]
#define SA 1024.0f        // emb scale (keeps lo-split out of fp16 subnormals)
#define SB 16384.0f       // diags scale
#define INV24 (5.9604644775390625e-8f)   // 2^-24

// Scan chunking
#define TCHUNK 32
#define NCHUNK (L_ / TCHUNK)   // 16
#define WARM   5
#define CS_STRIDE 160
#define KVBUF 3           // k2 pipeline depth-2 -> 3 LDS buffers

typedef _Float16 f16x8 __attribute__((ext_vector_type(8)));
typedef float f32x16 __attribute__((ext_vector_type(16)));

__device__ __forceinline__ float logsigf(float x) {
    // matches jax: -softplus(-x) = min(x,0) - log1p(exp(-|x|))
    return fminf(x, 0.f) - log1pf(expf(-fabsf(x)));
}

// fast variant for k1m epilogue: v_exp_f32/v_log_f32, abs err ~6e-8 (flip-safe budget)
__device__ __forceinline__ float logsigf_fast(float x) {
    return fminf(x, 0.f) - __logf(1.f + __expf(-fabsf(x)));
}

// async global->LDS, 16 B per lane; LDS dst = wave-uniform base + lane*16
__device__ __forceinline__ void gload_lds16(const void* gp, void* lp) {
    __builtin_amdgcn_global_load_lds(
        (const __attribute__((address_space(1))) unsigned int*)gp,
        (__attribute__((address_space(3))) unsigned int*)lp, 16, 0, 0);
}

// ---------------- MFMA path ----------------

// P12 (fused p1+p2, one launch):
// blocks [0, NVG*5): emb [300][20000] -> fp16 hi/lo splits, DMA-tiled
//   a_t[g 157][it 10][s 2][q 4][row 128] uint4.
// blocks [NVG*5, NVG*5+60): diags (dpm-mapped, scaled) -> b_t[j 6][it 10][s2][q4][row128].
__global__ __launch_bounds__(256) void p12_split(
    const float* __restrict__ emb, const float* __restrict__ diags,
    uint4* __restrict__ a_t, uint4* __restrict__ b_t)
{
    __shared__ float T[64][132];
    const int t   = threadIdx.x;
    const int bid = blockIdx.x;

    if (bid < NVG * 5) {
        // ---- p1 part ----
        const int gx = bid % NVG;
        const int ky = bid / NVG;            // 0..4
        const int v0 = gx * 128;
        const int k0 = ky * 64;

        #pragma unroll
        for (int pass = 0; pass < 8; ++pass) {
            int flat = pass * 256 + t;
            int krow = flat >> 5;
            int c4   = (flat & 31) * 4;
            int kg   = k0 + krow;
            int v    = v0 + c4;
            float4 f = {0.f, 0.f, 0.f, 0.f};
            if (kg < KDIM && v + 3 < V_)
                f = *(const float4*)(emb + (size_t)kg * V_ + v);
            *(float4*)&T[krow][c4] = f;
        }
        __syncthreads();

        const int vv = t >> 1;
        const int kh = (t & 1) * 32;
        const int it = ky * 2 + (kh >> 5);
        const int v  = v0 + vv;
        if (v < V_) {
            union { ushort u[8]; uint4 q; } H[4], Lo[4];
            #pragma unroll
            for (int i = 0; i < 32; ++i) {
                float x = T[kh + i][vv] * SA;
                __half h = __float2half_rn(x);
                float rem = x - __half2float(h);
                H[i >> 3].u[i & 7]  = __half_as_ushort(h);
                Lo[i >> 3].u[i & 7] = __half_as_ushort(__float2half_rn(rem));
            }
            uint4* tile = a_t + ((size_t)gx * NIT + it) * TILE_U4;
            #pragma unroll
            for (int c = 0; c < 4; ++c) {
                tile[      c * 128 + vv] = H[c].q;
                tile[512 + c * 128 + vv] = Lo[c].q;
            }
        }
    } else {
        // ---- p2 part ----
        const int bidx = bid - NVG * 5;      // j*10 + it, 0..59
        const int it   = bidx % NIT;
        const int j    = bidx / NIT;
        const int row  = t >> 1;
        const int qh   = (t & 1) * 2;
        const int n    = j * 128 + row;
        const bool nok = (n < NOUT);
        const int pm   = nok ? ((n / 5) * 6 + (n % 5)) : 0;
        uint4* tile = b_t + (size_t)bidx * TILE_U4;
        #pragma unroll
        for (int qq = 0; qq < 2; ++qq) {
            int q = qh + qq;
            union { ushort u[8]; uint4 v; } H, Lo;
            #pragma unroll
            for (int e = 0; e < 8; ++e) {
                int k = it * 32 + q * 8 + e;
                float x = (nok && k < KDIM) ? diags[(size_t)pm * KDIM + k] * SB : 0.f;
                __half h = __float2half_rn(x);
                float rem = x - __half2float(h);
                H.u[e]  = __half_as_ushort(h);
                Lo.u[e] = __half_as_ushort(__float2half_rn(rem));
            }
            tile[      q * 128 + row] = H.v;
            tile[512 + q * 128 + row] = Lo.v;
        }
    }
}

// K1 (MFMA, round-6): C = a1@b1 + a1@b2 + a2@b1 (fp16 split-f32), 128x128 tile,
// r0's 2-blocks/CU TLP structure + r5's B-direct-from-VMEM.
//
// Measured laws (r0..r5):
//  - k1m time ~ staged-DMA volume (r4 64KB/iter=91.6us, r5 32KB/iter=48us,
//    r0 32KB/iter/CU at 2blk=50us); compute and B-loads hide inside it.
//  - 2 blocks/CU doubles effective DMA rate vs 1 block/CU (cross-block TLP
//    covers the end-of-iter vmcnt(0) drain; r0 6.1 TB/s vs r5 1.6 TB/s agg).
//  - B-direct from b_t (983 KB, L2-resident) is free: issued BEFORE the
//    A-prefetch DMA so the MFMA B-wait is vmcnt(4), never draining it (r5).
//  - reg-staging without a pinned VGPR budget spills (r2/r3);
//    amdgpu_waves_per_eu(2,2) pins 2 waves/EU -> 256-VGPR budget (r4/r5).
// This round: A-only DMA 16 KB/iter/block (4 gload_lds16/wave), 2x16 KB LDS
// double-buffer, grid 960 XCD-swizzled (6 j-siblings of each a_t[g] per XCD).
// Staged aggregate 154 MB (r0: 307) at r0's rate -> predict ~25-30 us.
// Spill check: WRITE_SIZE must stay ~60 MB. Same MFMA order -> bitwise-same C.
__global__ __attribute__((amdgpu_waves_per_eu(2, 2))) __launch_bounds__(256)
void k1m_gemm(
    const uint4* __restrict__ a_t, const uint4* __restrict__ b_t,
    const float* __restrict__ bias, const float* __restrict__ wildc,
    float* __restrict__ cw)
{
    const int bid  = blockIdx.x;
    const int xcd  = bid & 7;
    const int slot = bid >> 3;               // 0..119
    const int g    = xcd + 8 * (slot / 6);   // v-group 0..159
    const int j    = slot % 6;               // n-group
    if (g >= NVG) return;

    __shared__ uint4 sm[2][1024];            // 2 x 16 KB (A only)
    const int t    = threadIdx.x;
    const int lane = t & 63;
    const int w    = t >> 6;                 // wave 0..3
    const int wr   = w >> 1, wc = w & 1;
    const int v0   = g * 128;
    const int n0   = j * 128;

    const int fk16 = lane >> 5;
    const int fm   = lane & 31;

    // A staging: wave w stages quarter w (256 u4 = 4 KB) of the 16 KB tile
    const uint4* asec = a_t + (size_t)g * NIT * TILE_U4 + w * 256 + lane;
    // B tile base (this block's n-group)
    const uint4* bbase = b_t + (size_t)j * NIT * TILE_U4;

    f32x16 acc[2][2];
    #pragma unroll
    for (int i = 0; i < 2; ++i)
        #pragma unroll
        for (int jj = 0; jj < 2; ++jj)
            #pragma unroll
            for (int e = 0; e < 16; ++e) acc[i][jj][e] = 0.f;

    // prologue: stage A it=0 into buffer 0
    #pragma unroll
    for (int i = 0; i < 4; ++i)
        gload_lds16(asec + i * 64, &sm[0][w * 256 + i * 64 + lane]);

    int cur = 0;
    for (int it = 0; it < NIT; ++it) {
        __syncthreads();                     // drains A-DMA for buf[cur]

        // 1) B fragment loads for THIS iter (plain VMEM, L2-resident),
        //    issued FIRST so the MFMA B-wait (vmcnt(4)) never drains the DMA.
        f16x8 B1[2][2], B2[2][2];            // [s][cj]
        #pragma unroll
        for (int s = 0; s < 2; ++s) {
            const int q = s * 2 + fk16;
            #pragma unroll
            for (int cj = 0; cj < 2; ++cj) {
                const uint4* bp = bbase + (size_t)it * TILE_U4
                                + q * 128 + wc * 64 + cj * 32 + fm;
                B1[s][cj] = *(const f16x8*)bp;
                B2[s][cj] = *(const f16x8*)(bp + 512);
            }
        }

        // 2) async A prefetch for it+1 into the other buffer
        if (it + 1 < NIT) {
            const uint4* ap = asec + (size_t)(it + 1) * TILE_U4;
            #pragma unroll
            for (int i = 0; i < 4; ++i)
                gload_lds16(ap + i * 64, &sm[cur ^ 1][w * 256 + i * 64 + lane]);
        }

        // 3) compute iter it: A from sm[cur] (linear copy of the a_t tile,
        //    [s 2][q 4][row 128] u4: hi at q*128+row, lo at +512), B from regs
        const uint4* smc = &sm[cur][0];
        #pragma unroll
        for (int s = 0; s < 2; ++s) {
            const int q = s * 2 + fk16;
            f16x8 A1[2], A2[2];
            #pragma unroll
            for (int ri = 0; ri < 2; ++ri) {
                const int ao = q * 128 + wr * 64 + ri * 32 + fm;
                A1[ri] = *(const f16x8*)&smc[ao];
                A2[ri] = *(const f16x8*)&smc[ao + 512];
            }
            #pragma unroll
            for (int ri = 0; ri < 2; ++ri)
                #pragma unroll
                for (int cj = 0; cj < 2; ++cj) {
                    acc[ri][cj] = __builtin_amdgcn_mfma_f32_32x32x16_f16(A1[ri], B1[s][cj], acc[ri][cj], 0, 0, 0);
                    acc[ri][cj] = __builtin_amdgcn_mfma_f32_32x32x16_f16(A1[ri], B2[s][cj], acc[ri][cj], 0, 0, 0);
                    acc[ri][cj] = __builtin_amdgcn_mfma_f32_32x32x16_f16(A2[ri], B1[s][cj], acc[ri][cj], 0, 0, 0);
                }
        }
        cur ^= 1;
    }

    // epilogue: C/D layout col=lane&31, row=(e&3)+8*(e>>2)+4*(lane>>5)
    float biasv[2], lwv[2]; int ncol[2]; bool nok[2];
    #pragma unroll
    for (int cj = 0; cj < 2; ++cj) {
        int n = n0 + wc * 64 + cj * 32 + fm;
        ncol[cj] = n;
        nok[cj]  = (n < NOUT);
        int nc = nok[cj] ? n : 0;
        int pm = (nc / 5) * 6 + (nc % 5);
        biasv[cj] = bias[pm];
        lwv[cj]   = logsigf_fast(wildc[nc]);
    }
    #pragma unroll
    for (int ri = 0; ri < 2; ++ri) {
        int vbase = v0 + wr * 64 + ri * 32 + 4 * fk16;
        #pragma unroll
        for (int cj = 0; cj < 2; ++cj) {
            if (!nok[cj]) continue;
            #pragma unroll
            for (int e = 0; e < 16; ++e) {
                int v = vbase + (e & 3) + 8 * (e >> 2);
                if (v < V_) {
                    float val = acc[ri][cj][e] * INV24 + biasv[cj];
                    cw[(size_t)v * CWS + ncol[cj]] = fmaxf(logsigf_fast(val), lwv[cj]);
                }
            }
        }
    }
}

// ---------------- f32 fallback (round-2 kernel) ----------------

__global__ __launch_bounds__(256) void k1_gemm_cw(
    const float* __restrict__ emb,
    const float* __restrict__ diags,
    const float* __restrict__ bias,
    const float* __restrict__ wildc,
    float* __restrict__ cw)
{
    __shared__ float As[BK][LDP];
    __shared__ float Bs[BK][LDP];

    const int tid = threadIdx.x;
    const int v0 = blockIdx.x * BM;
    const int n0 = blockIdx.y * BN;
    const int tx = tid & 15;
    const int ty = tid >> 4;

    float acc[8][8];
    #pragma unroll
    for (int i = 0; i < 8; ++i)
        #pragma unroll
        for (int j = 0; j < 8; ++j) acc[i][j] = 0.f;

    const int a_k = tid >> 4;
    const int a_v = (tid & 15) * 8;
    const int b_n   = tid >> 1;
    const int b_kof = (tid & 1) * 8;

    int  brow;
    bool bval;
    {
        int n = n0 + b_n;
        bval = (n < NOUT);
        brow = bval ? ((n / 5) * 6 + (n % 5)) : 0;
    }

    for (int k0 = 0; k0 < KDIM; k0 += BK) {
        {
            float4 f0 = {0,0,0,0}, f1 = {0,0,0,0};
            int k = k0 + a_k;
            if (k < KDIM) {
                const float* src = emb + (size_t)k * V_ + v0 + a_v;
                if (v0 + a_v + 3 < V_) f0 = *(const float4*)src;
                if (v0 + a_v + 7 < V_) f1 = *(const float4*)(src + 4);
            }
            *(float4*)&As[a_k][a_v]     = f0;
            *(float4*)&As[a_k][a_v + 4] = f1;
        }
        {
            float4 f = {0,0,0,0}, g = {0,0,0,0};
            if (bval) {
                const float* src = diags + (size_t)brow * KDIM + k0 + b_kof;
                if (k0 + b_kof + 3 < KDIM) f = *(const float4*)src;
                if (k0 + b_kof + 7 < KDIM) g = *(const float4*)(src + 4);
            }
            Bs[b_kof + 0][b_n] = f.x;
            Bs[b_kof + 1][b_n] = f.y;
            Bs[b_kof + 2][b_n] = f.z;
            Bs[b_kof + 3][b_n] = f.w;
            Bs[b_kof + 4][b_n] = g.x;
            Bs[b_kof + 5][b_n] = g.y;
            Bs[b_kof + 6][b_n] = g.z;
            Bs[b_kof + 7][b_n] = g.w;
        }
        __syncthreads();
        #pragma unroll
        for (int k = 0; k < BK; ++k) {
            float4 a0 = *(const float4*)&As[k][tx * 4];
            float4 a1 = *(const float4*)&As[k][64 + tx * 4];
            float4 b0 = *(const float4*)&Bs[k][ty * 8];
            float4 b1 = *(const float4*)&Bs[k][ty * 8 + 4];
            float av[8] = {a0.x, a0.y, a0.z, a0.w, a1.x, a1.y, a1.z, a1.w};
            float bv[8] = {b0.x, b0.y, b0.z, b0.w, b1.x, b1.y, b1.z, b1.w};
            #pragma unroll
            for (int i = 0; i < 8; ++i)
                #pragma unroll
                for (int j = 0; j < 8; ++j)
                    acc[i][j] = fmaf(av[i], bv[j], acc[i][j]);
        }
        __syncthreads();
    }

    float biasv[8], lwv[8];
    #pragma unroll
    for (int j = 0; j < 8; ++j) {
        int n  = n0 + ty * 8 + j;
        int nc = (n < NOUT) ? n : 0;
        int pm = (nc / 5) * 6 + (nc % 5);
        biasv[j] = bias[pm];
        lwv[j]   = logsigf(wildc[nc]);
    }
    #pragma unroll
    for (int i = 0; i < 8; ++i) {
        int v = v0 + ((i < 4) ? (tx * 4 + i) : (64 + tx * 4 + (i - 4)));
        if (v >= V_) continue;
        float r[8];
        #pragma unroll
        for (int j = 0; j < 8; ++j)
            r[j] = fmaxf(logsigf(acc[i][j] + biasv[j]), lwv[j]);
        float* dst = cw + (size_t)v * CWS + n0 + ty * 8;
        if (n0 + ty * 8     < NOUT) *(float4*)dst       = make_float4(r[0], r[1], r[2], r[3]);
        if (n0 + ty * 8 + 4 < NOUT) *(float4*)(dst + 4) = make_float4(r[4], r[5], r[6], r[7]);
    }
}

// ---------------- scan (pipelined LDS staging) + finalize ----------------

// 3-buffer, depth-2 pipeline with counted s_waitcnt vmcnt(3) + raw s_barrier
// (one barrier per round). Bit-identical values.
__global__ __launch_bounds__(192) void k2_scan(
    const int* __restrict__ docs,
    const int* __restrict__ doc_lens,
    const float* __restrict__ cw,
    float* __restrict__ cs)
{
    const int ci = blockIdx.x;
    const int b  = blockIdx.y;
    const int t0 = ci * TCHUNK;
    const int ts = (t0 >= WARM) ? (t0 - WARM) : 0;
    const int dl = doc_lens[b];
    const int te = min(t0 + TCHUNK, dl);
    const int nt = te - ts;              // tokens to process (may be <= 0)

    __shared__ int   toks[TCHUNK + WARM];
    __shared__ float rows[KVBUF][3][768];   // 27 KB: [buf][row-in-round][752 used]

    const int t    = threadIdx.x;
    const int lane = t & 63;
    const int w    = t >> 6;             // wave 0..2

    if (t < TCHUNK + WARM) {
        int tt = ts + t;
        toks[t] = docs[b * L_ + min(tt, L_ - 1)];
    }
    __syncthreads();                     // toks ready; drains all prior vmem

    const int p      = t;                // pattern if < P_
    const int e      = (p < 50) ? 3 : (p < 100) ? 4 : 5;
    const int warm_n = t0 - ts;
    float h1 = NEGF, h2 = NEGF, h3 = NEGF, h4 = NEGF, h5 = NEGF, sc = NEGF;

    const int nrounds = (nt > 0) ? (nt + 2) / 3 : 0;

    // prologue: issue DMA for rounds 0 and 1 (wave w stages row w of a round)
    for (int r0 = 0; r0 < 2; ++r0) {
        if (r0 >= nrounds) break;
        int idx = min(3 * r0 + w, nt - 1);
        const char* rowp = (const char*)(cw + (size_t)toks[idx] * CWS);
        char* lbase = (char*)&rows[r0][w][0];
        #pragma unroll
        for (int jj = 0; jj < 3; ++jj)
            gload_lds16(rowp + jj * 1024 + lane * 16,
                        lbase + jj * 1024 + lane * 16);
    }

    int bufc = 0;
    for (int r = 0; r < nrounds; ++r) {
        // drain THIS round's DMA only; keep round r+1's 3 loads in flight
        if (r + 1 < nrounds) {
            asm volatile("s_waitcnt vmcnt(3)" ::: "memory");
        } else {
            asm volatile("s_waitcnt vmcnt(0)" ::: "memory");
        }
        __builtin_amdgcn_s_barrier();
        asm volatile("" ::: "memory");   // fence: no rows-read hoists above barrier

        if (r + 2 < nrounds) {           // prefetch round r+2 (buffer of round r-1)
            int rn  = r + 2;
            int idx = min(3 * rn + w, nt - 1);
            const char* rowp = (const char*)(cw + (size_t)toks[idx] * CWS);
            int bn = bufc + 2; if (bn >= KVBUF) bn -= KVBUF;
            char* lbase = (char*)&rows[bn][w][0];
            #pragma unroll
            for (int jj = 0; jj < 3; ++jj)
                gload_lds16(rowp + jj * 1024 + lane * 16,
                            lbase + jj * 1024 + lane * 16);
        }

        #pragma unroll
        for (int u = 0; u < 3; ++u) {
            int i2 = 3 * r + u;
            if (i2 >= nt) break;
            if (p < P_) {
                const float* rp = &rows[bufc][u][p * 5];
                float c0 = rp[0], c1 = rp[1], c2 = rp[2], c3 = rp[3], c4 = rp[4];
                h5 = h4 + c4;
                h4 = h3 + c3;
                h3 = h2 + c2;
                h2 = h1 + c1;
                h1 = c0;                 // h0 = 0 always
                if (i2 >= warm_n) {
                    float esv = (e == 3) ? h3 : (e == 4) ? h4 : h5;
                    sc = fmaxf(sc, esv);
                }
            }
        }
        bufc = (bufc + 1 == KVBUF) ? 0 : bufc + 1;
        // no second barrier: the barrier at top of round r+1 orders
        // compute(r) (all waves) before DMA(r+3) overwrites buf[r%3]
    }
    if (p < P_) cs[(size_t)(b * NCHUNK + ci) * CS_STRIDE + p] = sc;
}

__device__ __forceinline__ float block_sum192(float v, volatile float* red, int tid) {
    #pragma unroll
    for (int off = 32; off > 0; off >>= 1) v += __shfl_down(v, off, 64);
    __syncthreads();
    if ((tid & 63) == 0) red[tid >> 6] = v;
    __syncthreads();
    return red[0] + red[1] + red[2];
}

__global__ __launch_bounds__(192) void k3_final(
    const float* __restrict__ cs,
    const float* __restrict__ gamma,
    const float* __restrict__ beta,
    const float* __restrict__ lw,
    const float* __restrict__ lb,
    float* __restrict__ out)
{
    __shared__ float red[3];
    const int b   = blockIdx.x;
    const int tid = threadIdx.x;
    float s = 0.f;
    if (tid < P_) {
        float m = NEGF;
        const float* row = cs + (size_t)b * NCHUNK * CS_STRIDE + tid;
        #pragma unroll
        for (int ci = 0; ci < NCHUNK; ++ci) m = fmaxf(m, row[ci * CS_STRIDE]);
        s = expf(m);
    }
    float mu = block_sum192(s, red, tid) * (1.f / P_);
    float d  = (tid < P_) ? (s - mu) : 0.f;
    float var = block_sum192(d * d, red, tid) * (1.f / P_);
    float bin = 0.f;
    if (tid < P_) {
        float norm = (s - mu) * rsqrtf(var + 1e-5f) * gamma[tid] + beta[tid];
        bin = (norm > 0.f) ? 1.f : 0.f;
    }
    float o0 = block_sum192((tid < P_) ? bin * lw[tid]      : 0.f, red, tid);
    float o1 = block_sum192((tid < P_) ? bin * lw[P_ + tid] : 0.f, red, tid);
    if (tid == 0) {
        out[b * 2 + 0] = o0 + lb[0];
        out[b * 2 + 1] = o1 + lb[1];
    }
}

extern "C" void kernel_launch(void* const* d_in, const int* in_sizes, int n_in,
                              void* d_out, int out_size, void* d_ws, size_t ws_size,
                              hipStream_t stream)
{
    const int*   docs  = (const int*)  d_in[0];
    const int*   dlens = (const int*)  d_in[1];
    const float* emb   = (const float*)d_in[2];
    const float* diags = (const float*)d_in[3];
    const float* bias  = (const float*)d_in[4];
    const float* wildc = (const float*)d_in[5];
    const float* gamma = (const float*)d_in[6];
    const float* beta  = (const float*)d_in[7];
    const float* lw    = (const float*)d_in[8];
    const float* lb    = (const float*)d_in[9];
    float* out = (float*)d_out;

    // ws layout: cw | cs | a_t | b_t
    const size_t cw_b = (size_t)V_ * CWS * 4;                 // 60,160,000
    const size_t cs_b = (size_t)B_ * NCHUNK * CS_STRIDE * 4;  // 655,360
    const size_t at_b = (size_t)NVG * NIT * TILE_U4 * 16;     // 25,722,880
    const size_t bt_b = (size_t)NJ  * NIT * TILE_U4 * 16;     // 983,040
    const size_t need = cw_b + cs_b + at_b + bt_b;

    char* base = (char*)d_ws;
    float* cw = (float*)base;
    float* cs = (float*)(base + cw_b);
    uint4* at = (uint4*)(base + cw_b + cs_b);
    uint4* bt = (uint4*)(base + cw_b + cs_b + at_b);

    if (ws_size >= need) {
        p12_split<<<NVG * 5 + NJ * NIT, 256, 0, stream>>>(emb, diags, at, bt);
        // 1-D grid, XCD-colocated siblings: 160 v-group slots x 6 n-groups = 960
        k1m_gemm<<<960, 256, 0, stream>>>(at, bt, bias, wildc, cw);
    } else {
        dim3 g1((V_ + BM - 1) / BM, (NOUT + BN - 1) / BN);
        k1_gemm_cw<<<g1, 256, 0, stream>>>(emb, diags, bias, wildc, cw);
    }

    dim3 g2(NCHUNK, B_);
    k2_scan<<<g2, 192, 0, stream>>>(docs, dlens, cw, cs);
    k3_final<<<B_, 192, 0, stream>>>(cs, gamma, beta, lw, lb, out);
}